// Round 2
// baseline (631.768 us; speedup 1.0000x reference)
//
#include <hip/hip_runtime.h>
#include <math.h>

// B=2, T=1024, C=4096, Hq=32, Hkv=8, D=128, G=4; start_pos on device (1024).
// I/O fp32; compute bf16 MFMA. d_out doubles as bf16 scratch before the final GEMM:
//   [0 .. 16.8MB)  qb   bf16 [b*1024+t][4096]   (q, RoPE'd, pre-scaled by 1/sqrt(D)*log2e)
//   [16.8 .. 25.2) KT   bf16 [b][kh][s<2048][d]
//   [25.2 .. 33.5) VT   bf16 [b][kh][d][s<2048]
// ws layout unchanged (full: bf16 weights; fallback: fp32 weights, old gemm path).

typedef __bf16 bf16x8 __attribute__((ext_vector_type(8)));
typedef float floatx4 __attribute__((ext_vector_type(4)));
typedef float floatx16 __attribute__((ext_vector_type(16)));

constexpr int SMAX = 2048;
constexpr size_t KT_OFF = (size_t)2 * 1024 * 4096;             // shorts
constexpr size_t VT_OFF = KT_OFF + (size_t)2 * 8 * SMAX * 128;
// ws offsets in shorts
constexpr size_t WS_XB = 0;
constexpr size_t WS_WQ = 8388608;
constexpr size_t WS_WK = 25165824;
constexpr size_t WS_WV = 29360128;
constexpr size_t WS_WO = 33554432;
constexpr size_t WS_FULL_BYTES = 100663296;

__device__ __forceinline__ unsigned short f2bf(float f) {
  union { float f; unsigned int u; } v; v.f = f;
  unsigned int u = v.u;
  return (unsigned short)((u + 0x7fffu + ((u >> 16) & 1u)) >> 16);
}

__device__ __forceinline__ bf16x8 pack8(float4 a, float4 b) {
  bf16x8 v;
  v[0] = (__bf16)a.x; v[1] = (__bf16)a.y; v[2] = (__bf16)a.z; v[3] = (__bf16)a.w;
  v[4] = (__bf16)b.x; v[5] = (__bf16)b.y; v[6] = (__bf16)b.z; v[7] = (__bf16)b.w;
  return v;
}

__device__ __forceinline__ unsigned cvtpk_bf16(float lo, float hi) {
  unsigned r;
  asm("v_cvt_pk_bf16_f32 %0, %1, %2" : "=v"(r) : "v"(lo), "v"(hi));
  return r;
}

// async global(16B/lane) -> LDS DMA; dest = wave-uniform base + lane*16
__device__ __forceinline__ void gll16(const unsigned short* g, unsigned short* l) {
  __builtin_amdgcn_global_load_lds((const __attribute__((address_space(1))) void*)g,
                                   (__attribute__((address_space(3))) void*)l, 16, 0, 0);
}

// --------------------------------------------------------------------------- fp32 -> bf16 converters
__global__ __launch_bounds__(256) void cvt_x(const float* __restrict__ x,
                                             unsigned short* __restrict__ xb) {
  for (size_t c = (size_t)blockIdx.x * 256 + threadIdx.x; c < 1048576; c += (size_t)gridDim.x * 256) {
    float4 f0 = ((const float4*)x)[c * 2], f1 = ((const float4*)x)[c * 2 + 1];
    ((bf16x8*)xb)[c] = pack8(f0, f1);
  }
}

__global__ __launch_bounds__(256) void cvt_full(const float* __restrict__ x,
                                                const float* __restrict__ wq,
                                                const float* __restrict__ wk,
                                                const float* __restrict__ wv,
                                                const float* __restrict__ wo,
                                                unsigned short* __restrict__ ws) {
  const size_t n0 = 1048576, n1 = n0 + 2097152, n2 = n1 + 524288, n3 = n2 + 524288, n4 = n3 + 2097152;
  for (size_t c = (size_t)blockIdx.x * 256 + threadIdx.x; c < n4; c += (size_t)gridDim.x * 256) {
    const float* src; unsigned short* dst; size_t off;
    if (c < n0)      { src = x;  dst = ws + WS_XB; off = c; }
    else if (c < n1) { src = wq; dst = ws + WS_WQ; off = c - n0; }
    else if (c < n2) { src = wk; dst = ws + WS_WK; off = c - n1; }
    else if (c < n3) { src = wv; dst = ws + WS_WV; off = c - n2; }
    else             { src = wo; dst = ws + WS_WO; off = c - n3; }
    float4 f0 = ((const float4*)src)[off * 2], f1 = ((const float4*)src)[off * 2 + 1];
    ((bf16x8*)dst)[off] = pack8(f0, f1);
  }
}

// --------------------------------------------------------------------------- tables
__global__ __launch_bounds__(256) void rope_prep(const int* __restrict__ spp,
                                                 float* __restrict__ tab) {
  int idx = blockIdx.x * 256 + threadIdx.x;   // 65536 entries: idx = t*64 + i
  int t = idx >> 6, i = idx & 63;
  float ang = (float)(spp[0] + t) * exp2f(-(float)i * 0.2076205059304602f);
  tab[idx] = sinf(ang);
  tab[65536 + idx] = cosf(ang);
}

// --------------------------------------------------------------------------- old cache -> bf16 KT/VT
__global__ __launch_bounds__(256) void convert_cache(const float* __restrict__ ck,
                                                     const float* __restrict__ cv,
                                                     const int* __restrict__ spp,
                                                     unsigned short* __restrict__ kt,
                                                     unsigned short* __restrict__ vt) {
  const int sp = spp[0];
  const int bk = blockIdx.y;           // b*8+kh
  const int b = bk >> 3, kh = bk & 7;
  const int s1 = blockIdx.x * 128;
  if (s1 >= sp) return;
  const int tid = threadIdx.x;
#pragma unroll
  for (int it = 0; it < 8; ++it) {     // K: 2048 chunks x 8 d
    int c = tid + it * 256;
    int s = c >> 4, dc = (c & 15) * 8;
    if (s1 + s < sp) {
      const float* src = ck + (((size_t)(b * 4096 + s1 + s)) * 8 + kh) * 128 + dc;
      *(bf16x8*)(kt + ((size_t)bk * SMAX + s1 + s) * 128 + dc) = pack8(*(const float4*)src, *(const float4*)(src + 4));
    }
  }
#pragma unroll
  for (int it = 0; it < 8; ++it) {     // V -> VT: 128 d x 16 s-groups of 8
    int c = tid + it * 256;
    int d = c & 127, sg = c >> 7;
    bf16x8 tmp;
#pragma unroll
    for (int ss = 0; ss < 8; ++ss) {
      int s = s1 + sg * 8 + ss;
      tmp[ss] = (s < sp) ? (__bf16)cv[(((size_t)(b * 4096 + s)) * 8 + kh) * 128 + d] : (__bf16)0.0f;
    }
    *(bf16x8*)(vt + (size_t)bk * 128 * SMAX + (size_t)d * SMAX + s1 + sg * 8) = tmp;
  }
}

// --------------------------------------------------------------------------- deep-pipelined GEMM (T2+T4+T5)
// C[m][n] = sum_k A[m][k]*B[n][k]; A,B bf16 row-major K=4096. Block tile BM x 256.
// Ring of 4 K-tile LDS slots (BK=32), prefetch depth 3, counted vmcnt (never 0 in
// steady state), raw s_barrier (no compiler vmcnt drain), XOR-swizzled LDS slots
// (swizzle applied to global_load_lds SOURCE addr + ds_read addr; LDS dest linear),
// setprio(1) around MFMA clusters. EPI 0: fp32 out (Wo). EPI 1: QKV rope/scatter.
template<int BM, int EPI>
__global__ __launch_bounds__(512, 2) void gemm8(const unsigned short* __restrict__ A,
                                                const unsigned short* __restrict__ B,
                                                float* __restrict__ Cout,
                                                unsigned short* __restrict__ qb,
                                                unsigned short* __restrict__ kt,
                                                unsigned short* __restrict__ vt,
                                                const float* __restrict__ tab,
                                                const int* __restrict__ spp) {
  extern __shared__ unsigned short lds[];
  constexpr int K = 4096;
  constexpr int NT = K / 32;                  // 128 K-tiles
  constexpr int ASLOT = BM * 32;              // shorts
  constexpr int SLOT = ASLOT + 256 * 32;      // shorts per ring slot
  constexpr int MI = (BM == 256) ? 8 : 4;
  constexpr int NTN = (EPI == 1) ? 24 : 16;   // N-tiles (N = 6144 / 4096)
  constexpr int NWG = (EPI == 1) ? 192 : 256;

  const int tid = threadIdx.x, lane = tid & 63, w = tid >> 6;
  const int l16 = lane & 15, quad = lane >> 4;
  const int wr = w >> 2, wc = w & 3;

  // bijective XCD remap (m204): XCD x owns a contiguous chunk of logical blocks.
  const int bid = blockIdx.x;
  const int lb = (bid & 7) * (NWG >> 3) + (bid >> 3);
  const int mt = lb / NTN, nt = lb % NTN;
  const int m0 = mt * BM, n0 = nt * 256;
  const int sp = spp ? spp[0] : 0;

  // staging lane math: lane l writes phys 16B-slot (l&3) of row (l>>2) within a
  // 16-row group; sources logical slot (l&3)^((l>>3)&3)  [involution == read swizzle]
  const int lrow = lane >> 2;
  const int lslot = (lane & 3) ^ ((lane >> 3) & 3);
  const unsigned short* ag = A + (size_t)(m0 + ((BM == 256) ? (w * 32) : (w * 16)) + lrow) * K + lslot * 8;
  const unsigned short* bg = B + (size_t)(n0 + w * 32 + lrow) * K + lslot * 8;
  const int adst0 = ((BM == 256) ? (w * 32) : (w * 16)) * 32;   // shorts within slot
  const int bdst0 = ASLOT + (w * 32) * 32;

  // frag read offsets: logical k-chunk quad at row r lives at phys quad^((r>>1)&3);
  // all frag rows are ≡ l16 (mod 16-row groups) -> lane-constant XOR.
  const int fslot = (quad ^ ((l16 >> 1) & 3)) * 8;
  const int abase = ((BM == 256 ? wr * 128 : wr * 64) + l16) * 32 + fslot;
  const int bbase = ASLOT + (wc * 64 + l16) * 32 + fslot;

  floatx4 acc[MI][4] = {};

  auto stage = [&](int t) {
    unsigned short* sb = lds + (t & 3) * SLOT;
    const int ko = t * 32;
    gll16(ag + ko, sb + adst0);
    if constexpr (BM == 256) gll16(ag + (size_t)16 * K + ko, sb + adst0 + 16 * 32);
    gll16(bg + ko, sb + bdst0);
    gll16(bg + (size_t)16 * K + ko, sb + bdst0 + 16 * 32);
  };

  auto compute = [&](int t) {
    const unsigned short* sb = lds + (t & 3) * SLOT;
    bf16x8 bfr[4];
#pragma unroll
    for (int ni = 0; ni < 4; ++ni)
      bfr[ni] = *(const bf16x8*)(sb + bbase + ni * 512);
    bf16x8 af[4];
#pragma unroll
    for (int mi = 0; mi < 4; ++mi)
      af[mi] = *(const bf16x8*)(sb + abase + mi * 512);
    __builtin_amdgcn_s_setprio(1);
#pragma unroll
    for (int mi = 0; mi < 4; ++mi)
#pragma unroll
      for (int ni = 0; ni < 4; ++ni)
        acc[mi][ni] = __builtin_amdgcn_mfma_f32_16x16x32_bf16(af[mi], bfr[ni], acc[mi][ni], 0, 0, 0);
    __builtin_amdgcn_s_setprio(0);
    if constexpr (BM == 256) {
      bf16x8 af2[4];
#pragma unroll
      for (int mi = 0; mi < 4; ++mi)
        af2[mi] = *(const bf16x8*)(sb + abase + (mi + 4) * 512);
      __builtin_amdgcn_s_setprio(1);
#pragma unroll
      for (int mi = 0; mi < 4; ++mi)
#pragma unroll
        for (int ni = 0; ni < 4; ++ni)
          acc[mi + 4][ni] = __builtin_amdgcn_mfma_f32_16x16x32_bf16(af2[mi], bfr[ni], acc[mi + 4][ni], 0, 0, 0);
      __builtin_amdgcn_s_setprio(0);
    }
  };

  stage(0); stage(1); stage(2);   // prefetch depth 3
  for (int t = 0; t < NT; ++t) {
    if (t + 3 < NT) {
      stage(t + 3);               // targets slot (t-1)&3: reads finished last iter
      if constexpr (BM == 256) asm volatile("s_waitcnt vmcnt(12)" ::: "memory");
      else                     asm volatile("s_waitcnt vmcnt(9)" ::: "memory");
    } else if (t + 3 == NT) {
      if constexpr (BM == 256) asm volatile("s_waitcnt vmcnt(8)" ::: "memory");
      else                     asm volatile("s_waitcnt vmcnt(6)" ::: "memory");
    } else if (t + 2 == NT) {
      if constexpr (BM == 256) asm volatile("s_waitcnt vmcnt(4)" ::: "memory");
      else                     asm volatile("s_waitcnt vmcnt(3)" ::: "memory");
    } else {
      asm volatile("s_waitcnt vmcnt(0)" ::: "memory");
    }
    __builtin_amdgcn_s_barrier();            // tile t resident for ALL waves
    __builtin_amdgcn_sched_barrier(0);       // no ds_read hoists above barrier
    compute(t);
    asm volatile("s_waitcnt lgkmcnt(0)" ::: "memory");  // my tile-t reads drained
    __builtin_amdgcn_sched_barrier(0);
    __builtin_amdgcn_s_barrier();            // all waves done reading slot t&3
  }

  if constexpr (EPI == 0) {
#pragma unroll
    for (int mi = 0; mi < MI; ++mi)
#pragma unroll
      for (int r = 0; r < 4; ++r) {
        const int row = m0 + wr * (BM / 2) + mi * 16 + quad * 4 + r;
#pragma unroll
        for (int ni = 0; ni < 4; ++ni)
          Cout[(size_t)row * 4096 + n0 + wc * 64 + ni * 16 + l16] = acc[mi][ni][r];
      }
  } else {
    const float S_L2E = 0.12751745f;  // (1/sqrt(128)) * log2(e)
#pragma unroll
    for (int mi = 0; mi < MI; ++mi) {
#pragma unroll
      for (int r = 0; r < 4; ++r) {
        const int row = m0 + wr * (BM / 2) + mi * 16 + quad * 4 + r;
        const int bb = row >> 10, tt = row & 1023;
#pragma unroll
        for (int ni = 0; ni < 4; ++ni) {
          const int col = n0 + wc * 64 + ni * 16 + l16;
          float v = acc[mi][ni][r];
          if (col < 5120) {  // q or k: RoPE (wave-uniform outer branch)
            int dd = col & 127, i = dd >> 1;
            float sn = tab[tt * 64 + i], cs = tab[65536 + tt * 64 + i];
            float vp = __shfl_xor(v, 1, 64);
            float o = (dd & 1) ? (vp * sn + v * cs) : (v * cs - vp * sn);
            if (col < 4096) {
              qb[(size_t)row * 4096 + col] = f2bf(o * S_L2E);
            } else {
              int lc = col - 4096, kh = lc >> 7, d = lc & 127;
              kt[((size_t)(bb * 8 + kh) * SMAX + sp + tt) * 128 + d] = f2bf(o);
            }
          } else {
            int lc = col - 5120, kh = lc >> 7, d = lc & 127;
            vt[((size_t)(bb * 8 + kh) * 128 + d) * SMAX + sp + tt] = f2bf(v);
          }
        }
      }
    }
  }
}

// --------------------------------------------------------------------------- old unified GEMM core (fallback path)
template<bool BDMA, int EPI>
__global__ __launch_bounds__(256) void gemm_core(const unsigned short* __restrict__ A,
                                                 const unsigned short* __restrict__ Bb,
                                                 const float* __restrict__ Bq,
                                                 const float* __restrict__ Bk,
                                                 const float* __restrict__ Bv,
                                                 float* __restrict__ Cout,
                                                 unsigned short* __restrict__ qb,
                                                 unsigned short* __restrict__ kt,
                                                 unsigned short* __restrict__ vt,
                                                 const float* __restrict__ tab,
                                                 const int* __restrict__ spp) {
  constexpr int SB = BDMA ? 32 : 40;
  __shared__ __align__(16) unsigned short la[128 * 32];
  __shared__ __align__(16) unsigned short lb[128 * SB];
  const int K = 4096;
  const int tid = threadIdx.x, lane = tid & 63, wv = tid >> 6;
  const int quad = lane >> 4, l16 = lane & 15;
  const int wm = (wv >> 1) * 64, wn = (wv & 1) * 64;
  const int m0 = blockIdx.y * 128, n0 = blockIdx.x * 128;
  const int sp = spp ? spp[0] : 0;

  floatx4 acc[4][4] = {};

  const int r0 = tid >> 2, kc0 = (tid & 3) * 8;
  const int r1 = (tid + 256) >> 2, kc1 = ((tid + 256) & 3) * 8;
  const unsigned short* a0 = A + (size_t)(m0 + r0) * K + kc0;
  const unsigned short* a1 = A + (size_t)(m0 + r1) * K + kc1;

  const unsigned short* bh0 = nullptr; const unsigned short* bh1 = nullptr;
  const float* bf0 = nullptr; const float* bf1 = nullptr;
  if (BDMA) {
    bh0 = Bb + (size_t)(n0 + r0) * K + kc0;
    bh1 = Bb + (size_t)(n0 + r1) * K + kc1;
  } else {
    const float* Bf; int nb;
    if (EPI == 0)      { Bf = Bq; nb = n0; }
    else {
      if (n0 < 4096)      { Bf = Bq; nb = n0; }
      else if (n0 < 5120) { Bf = Bk; nb = n0 - 4096; }
      else                { Bf = Bv; nb = n0 - 5120; }
    }
    bf0 = Bf + (size_t)(nb + r0) * K + kc0;
    bf1 = Bf + (size_t)(nb + r1) * K + kc1;
  }

  for (int k0 = 0; k0 < K; k0 += 32) {
    gll16(a0 + k0, la + tid * 8);
    gll16(a1 + k0, la + (tid + 256) * 8);
    if (BDMA) {
      gll16(bh0 + k0, lb + tid * 8);
      gll16(bh1 + k0, lb + (tid + 256) * 8);
    } else {
      bf16x8 vb0 = pack8(*(const float4*)(bf0 + k0), *(const float4*)(bf0 + k0 + 4));
      bf16x8 vb1 = pack8(*(const float4*)(bf1 + k0), *(const float4*)(bf1 + k0 + 4));
      *(bf16x8*)(lb + r0 * 40 + kc0) = vb0;
      *(bf16x8*)(lb + r1 * 40 + kc1) = vb1;
    }
    __syncthreads();
    bf16x8 af[4], bfr[4];
#pragma unroll
    for (int mi = 0; mi < 4; ++mi)
      af[mi] = *(const bf16x8*)(la + (wm + mi * 16 + l16) * 32 + quad * 8);
#pragma unroll
    for (int ni = 0; ni < 4; ++ni)
      bfr[ni] = *(const bf16x8*)(lb + (wn + ni * 16 + l16) * SB + quad * 8);
#pragma unroll
    for (int mi = 0; mi < 4; ++mi)
#pragma unroll
      for (int ni = 0; ni < 4; ++ni)
        acc[mi][ni] = __builtin_amdgcn_mfma_f32_16x16x32_bf16(af[mi], bfr[ni], acc[mi][ni], 0, 0, 0);
    __syncthreads();
  }

  if (EPI == 0) {
#pragma unroll
    for (int mi = 0; mi < 4; ++mi)
#pragma unroll
      for (int r = 0; r < 4; ++r) {
        const int row = m0 + wm + mi * 16 + quad * 4 + r;
#pragma unroll
        for (int ni = 0; ni < 4; ++ni)
          Cout[(size_t)row * 4096 + n0 + wn + ni * 16 + l16] = acc[mi][ni][r];
      }
  } else {
    const float S_L2E = 0.12751745f;
#pragma unroll
    for (int mi = 0; mi < 4; ++mi) {
#pragma unroll
      for (int r = 0; r < 4; ++r) {
        const int row = m0 + wm + mi * 16 + quad * 4 + r;
        const int b = row >> 10, t = row & 1023;
#pragma unroll
        for (int ni = 0; ni < 4; ++ni) {
          const int col = n0 + wn + ni * 16 + l16;
          float v = acc[mi][ni][r];
          if (col < 5120) {
            int dd = col & 127, i = dd >> 1;
            float sn = tab[t * 64 + i], cs = tab[65536 + t * 64 + i];
            float vp = __shfl_xor(v, 1, 64);
            float o = (dd & 1) ? (vp * sn + v * cs) : (v * cs - vp * sn);
            if (col < 4096) {
              qb[(size_t)row * 4096 + col] = f2bf(o * S_L2E);
            } else {
              int lc = col - 4096, kh = lc >> 7, d = lc & 127;
              kt[((size_t)(b * 8 + kh) * SMAX + sp + t) * 128 + d] = f2bf(o);
            }
          } else {
            int lc = col - 5120, kh = lc >> 7, d = lc & 127;
            vt[((size_t)(b * 8 + kh) * 128 + d) * SMAX + sp + t] = f2bf(v);
          }
        }
      }
    }
  }
}

// --------------------------------------------------------------------------- flash attention (round-1, proven)
__global__ __launch_bounds__(512, 2) void attn(const unsigned short* __restrict__ qb,
                                               const unsigned short* __restrict__ ktg,
                                               const unsigned short* __restrict__ vtg,
                                               const int* __restrict__ spp,
                                               unsigned short* __restrict__ ctx) {
  __shared__ __align__(16) unsigned short lds[32768];

  const int sp = spp[0];
  const int iblk = (int)blockIdx.y * 4 + (int)blockIdx.x;
  const int lblk = (iblk & 7) * 32 + (iblk >> 3);
  const int x = lblk & 3, bh = lblk >> 2;
  const int b = bh >> 5, h = bh & 31;
  const int bk = b * 8 + (h >> 2);
  const int tid = threadIdx.x, lane = tid & 63, w = tid >> 6;
  const int hi = lane >> 5, l31 = lane & 31;
  const int tq128 = (w < 4) ? x : (7 - x);
  const int wq0 = tq128 * 128 + (w & 3) * 32;
  const int q = wq0 + l31;
  const int lim = sp + q;
  const int wlim = sp + wq0 + 31;
  const int nt = (sp + (8 - x) * 128 + 63) >> 6;

  const unsigned short* ktb = ktg + (size_t)bk * SMAX * 128;
  const unsigned short* vtb = vtg + (size_t)bk * 128 * SMAX;

  const int kr0 = tid >> 4, kc = tid & 15, kr1 = kr0 + 32;
  const int ksl0 = ((kc ^ (kr0 & 15)) << 3), ksl1 = ((kc ^ (kr1 & 15)) << 3);
  const int vd0 = tid >> 3, vc = tid & 7, vd1 = vd0 + 64;
  const int vsl0 = ((vc ^ (vd0 & 7)) << 3), vsl1 = ((vc ^ (vd1 & 7)) << 3);

  bf16x8 qf[8];
  {
    const unsigned short* qbase = qb + ((size_t)(b * 1024 + q)) * 4096 + h * 128 + hi * 8;
#pragma unroll
    for (int kg = 0; kg < 8; ++kg) qf[kg] = *(const bf16x8*)(qbase + kg * 16);
  }

  floatx16 oacc[4] = {};
  float mrun = -1e30f, lrun = 0.0f;

  *(bf16x8*)(lds + kr0 * 128 + ksl0)         = *(const bf16x8*)(ktb + (size_t)kr0 * 128 + kc * 8);
  *(bf16x8*)(lds + kr1 * 128 + ksl1)         = *(const bf16x8*)(ktb + (size_t)kr1 * 128 + kc * 8);
  *(bf16x8*)(lds + 16384 + vd0 * 64 + vsl0)  = *(const bf16x8*)(vtb + (size_t)vd0 * SMAX + vc * 8);
  *(bf16x8*)(lds + 16384 + vd1 * 64 + vsl1)  = *(const bf16x8*)(vtb + (size_t)vd1 * SMAX + vc * 8);
  __syncthreads();

  int off = 0;
  for (int st = 0; st < nt; ++st) {
    const int s0 = st * 64;
    bf16x8 nk0, nk1, nv0, nv1;
    const bool pre = (st + 1 < nt);
    if (pre) {
      const int s1 = s0 + 64;
      nk0 = *(const bf16x8*)(ktb + (size_t)(s1 + kr0) * 128 + kc * 8);
      nk1 = *(const bf16x8*)(ktb + (size_t)(s1 + kr1) * 128 + kc * 8);
      nv0 = *(const bf16x8*)(vtb + (size_t)vd0 * SMAX + s1 + vc * 8);
      nv1 = *(const bf16x8*)(vtb + (size_t)vd1 * SMAX + s1 + vc * 8);
      asm volatile("" ::: "memory");
    }
    const unsigned short* kl = lds + off;
    const unsigned short* vl = lds + 16384 + off;
    if (s0 <= wlim) {
#pragma unroll
      for (int sub = 0; sub < 2; ++sub) {
        const int ss = s0 + sub * 32;
        if (ss <= wlim) {
          floatx16 sa = {0,0,0,0,0,0,0,0,0,0,0,0,0,0,0,0};
          const unsigned short* kbase = kl + (sub * 32 + l31) * 128;
          const int kx = l31 & 15;
#pragma unroll
          for (int kg = 0; kg < 8; ++kg) {
            bf16x8 kf = *(const bf16x8*)(kbase + (((kg * 2 + hi) ^ kx) << 3));
            sa = __builtin_amdgcn_mfma_f32_32x32x16_bf16(kf, qf[kg], sa, 0, 0, 0);
          }
          if (ss + 31 > sp + wq0) {
#pragma unroll
            for (int r = 0; r < 16; ++r) {
              const int j = ss + (r & 3) + 8 * (r >> 2) + 4 * hi;
              if (j > lim) sa[r] = -1e30f;
            }
          }
          float mt = sa[0];
#pragma unroll
          for (int r = 1; r < 16; ++r) mt = fmaxf(mt, sa[r]);
          mt = fmaxf(mt, __shfl_xor(mt, 32, 64));
          if (!__all(mt <= mrun + 8.0f)) {
            const float mnew = fmaxf(mrun, mt);
            const float al = exp2f(mrun - mnew);
#pragma unroll
            for (int db = 0; db < 4; ++db)
#pragma unroll
              for (int r = 0; r < 16; ++r) oacc[db][r] *= al;
            lrun *= al;
            mrun = mnew;
          }
          float p[16]; float ls = 0.0f;
#pragma unroll
          for (int r = 0; r < 16; ++r) { p[r] = exp2f(sa[r] - mrun); ls += p[r]; }
          lrun += ls + __shfl_xor(ls, 32, 64);
#pragma unroll
          for (int ks = 0; ks < 2; ++ks) {
            const int rb = ks * 8;
            unsigned a0 = cvtpk_bf16(p[rb + 0], p[rb + 1]);
            unsigned a1 = cvtpk_bf16(p[rb + 2], p[rb + 3]);
            unsigned b0 = cvtpk_bf16(p[rb + 4], p[rb + 5]);
            unsigned b1 = cvtpk_bf16(p[rb + 6], p[rb + 7]);
            const unsigned t0 = __shfl_xor(a0, 32, 64);
            const unsigned t1 = __shfl_xor(b0, 32, 64);
            const unsigned t2 = __shfl_xor(a1, 32, 64);
            const unsigned t3 = __shfl_xor(b1, 32, 64);
            union { unsigned u[4]; bf16x8 v; } pf;
            pf.u[0] = hi ? t1 : a0;
            pf.u[1] = hi ? t3 : a1;
            pf.u[2] = hi ? b0 : t0;
            pf.u[3] = hi ? b1 : t2;
            const int sslot = sub * 4 + ks * 2 + hi;
#pragma unroll
            for (int db = 0; db < 4; ++db) {
              const int vrow = db * 32 + l31;
              bf16x8 vf = *(const bf16x8*)(vl + vrow * 64 + ((sslot ^ (l31 & 7)) << 3));
              oacc[db] = __builtin_amdgcn_mfma_f32_32x32x16_bf16(vf, pf.v, oacc[db], 0, 0, 0);
            }
          }
        }
      }
    }
    if (pre) {
      unsigned short* kn = lds + (off ^ 8192);
      unsigned short* vn = lds + 16384 + (off ^ 8192);
      *(bf16x8*)(kn + kr0 * 128 + ksl0) = nk0;
      *(bf16x8*)(kn + kr1 * 128 + ksl1) = nk1;
      *(bf16x8*)(vn + vd0 * 64 + vsl0) = nv0;
      *(bf16x8*)(vn + vd1 * 64 + vsl1) = nv1;
    }
    __syncthreads();
    off ^= 8192;
  }

  const float invl = 1.0f / lrun;
  unsigned short* myo = lds + w * 4096;
#pragma unroll
  for (int db = 0; db < 4; ++db)
#pragma unroll
    for (int i2 = 0; i2 < 8; ++i2) {
      const int r = i2 * 2;
      const int d = db * 32 + (r & 3) + 8 * (r >> 2) + 4 * hi;
      const unsigned wo = cvtpk_bf16(oacc[db][r] * invl, oacc[db][r + 1] * invl);
      *(unsigned*)(myo + l31 * 128 + (((2 * d) ^ ((l31 & 15) << 4)) >> 1)) = wo;
    }
  __syncthreads();
#pragma unroll
  for (int it = 0; it < 8; ++it) {
    const int c = tid + it * 512;
    const int wr = c >> 9, row = (c >> 4) & 31, c16 = c & 15;
    const int tq = (((wr < 4) ? x : (7 - x)) * 128) + (wr & 3) * 32 + row;
    bf16x8 vv = *(const bf16x8*)(lds + wr * 4096 + row * 128 + ((c16 ^ (row & 15)) << 3));
    *(bf16x8*)(ctx + ((size_t)(b * 1024 + tq)) * 4096 + h * 128 + c16 * 8) = vv;
  }
}

// ---------------------------------------------------------------------------
extern "C" void kernel_launch(void* const* d_in, const int* in_sizes, int n_in,
                              void* d_out, int out_size, void* d_ws, size_t ws_size,
                              hipStream_t stream) {
  const float* x  = (const float*)d_in[0];
  const int* sp   = (const int*)d_in[1];
  float* ck       = (float*)d_in[2];
  const float* cv = (const float*)d_in[3];
  const float* Wq = (const float*)d_in[4];
  const float* Wk = (const float*)d_in[5];
  const float* Wv = (const float*)d_in[6];
  const float* Wo = (const float*)d_in[7];
  float* out      = (float*)d_out;

  unsigned short* qb  = (unsigned short*)d_out;
  unsigned short* kt  = (unsigned short*)d_out + KT_OFF;
  unsigned short* vt  = (unsigned short*)d_out + VT_OFF;
  unsigned short* ws  = (unsigned short*)d_ws;
  unsigned short* xb  = ws + WS_XB;                 // shares [0,16.8MB) with ctx (disjoint lifetime)
  unsigned short* ctx = ws + WS_XB;
  float* tab          = ck + (size_t)2048 * 1024;   // unused cache_keys tail

  const bool full = ws_size >= WS_FULL_BYTES;

  rope_prep<<<256, 256, 0, stream>>>(sp, tab);
  convert_cache<<<dim3(16, 16), 256, 0, stream>>>(ck, cv, sp, kt, vt);

  bool ok8 = false;
  if (full) {
    ok8 = (hipFuncSetAttribute((const void*)gemm8<256, 1>,
                               hipFuncAttributeMaxDynamicSharedMemorySize, 131072) == hipSuccess) &&
          (hipFuncSetAttribute((const void*)gemm8<128, 0>,
                               hipFuncAttributeMaxDynamicSharedMemorySize, 98304) == hipSuccess);
  }

  if (full && ok8) {
    cvt_full<<<2048, 256, 0, stream>>>(x, Wq, Wk, Wv, Wo, ws);
    gemm8<256, 1><<<192, 512, 131072, stream>>>(xb, ws + WS_WQ, nullptr, qb, kt, vt, tab, sp);
    attn<<<dim3(4, 64), 512, 0, stream>>>(qb, kt, vt, sp, ctx);
    gemm8<128, 0><<<256, 512, 98304, stream>>>(ctx, ws + WS_WO, out, nullptr, nullptr, nullptr,
                                               nullptr, nullptr);
  } else if (full) {
    cvt_full<<<2048, 256, 0, stream>>>(x, Wq, Wk, Wv, Wo, ws);
    gemm_core<true, 1><<<dim3(48, 16), 256, 0, stream>>>(xb, ws + WS_WQ, nullptr, nullptr, nullptr,
                                                         nullptr, qb, kt, vt, tab, sp);
    attn<<<dim3(4, 64), 512, 0, stream>>>(qb, kt, vt, sp, ctx);
    gemm_core<true, 0><<<dim3(32, 16), 256, 0, stream>>>(ctx, ws + WS_WO, nullptr, nullptr, nullptr,
                                                         out, nullptr, nullptr, nullptr, nullptr, nullptr);
  } else {
    cvt_x<<<2048, 256, 0, stream>>>(x, xb);
    gemm_core<false, 1><<<dim3(48, 16), 256, 0, stream>>>(xb, nullptr, Wq, Wk, Wv,
                                                          nullptr, qb, kt, vt, tab, sp);
    attn<<<dim3(4, 64), 512, 0, stream>>>(qb, kt, vt, sp, ctx);
    gemm_core<false, 0><<<dim3(32, 16), 256, 0, stream>>>(ctx, nullptr, Wo, nullptr, nullptr,
                                                          out, nullptr, nullptr, nullptr, nullptr, nullptr);
  }
}

// Round 3
// 609.892 us; speedup vs baseline: 1.0359x; 1.0359x over previous
//
#include <hip/hip_runtime.h>
#include <math.h>

// B=2, T=1024, C=4096, Hq=32, Hkv=8, D=128, G=4; start_pos on device (1024).
// I/O fp32; compute bf16 MFMA. d_out doubles as bf16 scratch before the final GEMM:
//   [0 .. 16.8MB)  qb   bf16 [b*1024+t][4096]   (q, RoPE'd, pre-scaled by 1/sqrt(D)*log2e)
//   [16.8 .. 25.2) KT   bf16 [b][kh][s<2048][d]
//   [25.2 .. 33.5) VT   bf16 [b][kh][d][s<2048]
// ws layout unchanged (full: bf16 weights; fallback: fp32 weights, old gemm path).

typedef __bf16 bf16x8 __attribute__((ext_vector_type(8)));
typedef float floatx4 __attribute__((ext_vector_type(4)));
typedef float floatx16 __attribute__((ext_vector_type(16)));

constexpr int SMAX = 2048;
constexpr size_t KT_OFF = (size_t)2 * 1024 * 4096;             // shorts
constexpr size_t VT_OFF = KT_OFF + (size_t)2 * 8 * SMAX * 128;
// ws offsets in shorts
constexpr size_t WS_XB = 0;
constexpr size_t WS_WQ = 8388608;
constexpr size_t WS_WK = 25165824;
constexpr size_t WS_WV = 29360128;
constexpr size_t WS_WO = 33554432;
constexpr size_t WS_FULL_BYTES = 100663296;

__device__ __forceinline__ unsigned short f2bf(float f) {
  union { float f; unsigned int u; } v; v.f = f;
  unsigned int u = v.u;
  return (unsigned short)((u + 0x7fffu + ((u >> 16) & 1u)) >> 16);
}

__device__ __forceinline__ bf16x8 pack8(float4 a, float4 b) {
  bf16x8 v;
  v[0] = (__bf16)a.x; v[1] = (__bf16)a.y; v[2] = (__bf16)a.z; v[3] = (__bf16)a.w;
  v[4] = (__bf16)b.x; v[5] = (__bf16)b.y; v[6] = (__bf16)b.z; v[7] = (__bf16)b.w;
  return v;
}

__device__ __forceinline__ unsigned cvtpk_bf16(float lo, float hi) {
  unsigned r;
  asm("v_cvt_pk_bf16_f32 %0, %1, %2" : "=v"(r) : "v"(lo), "v"(hi));
  return r;
}

// async global(16B/lane) -> LDS DMA; dest = wave-uniform base + lane*16
__device__ __forceinline__ void gll16(const unsigned short* g, unsigned short* l) {
  __builtin_amdgcn_global_load_lds((const __attribute__((address_space(1))) void*)g,
                                   (__attribute__((address_space(3))) void*)l, 16, 0, 0);
}

// --------------------------------------------------------------------------- fp32 -> bf16 converters
__global__ __launch_bounds__(256) void cvt_x(const float* __restrict__ x,
                                             unsigned short* __restrict__ xb) {
  for (size_t c = (size_t)blockIdx.x * 256 + threadIdx.x; c < 1048576; c += (size_t)gridDim.x * 256) {
    float4 f0 = ((const float4*)x)[c * 2], f1 = ((const float4*)x)[c * 2 + 1];
    ((bf16x8*)xb)[c] = pack8(f0, f1);
  }
}

__global__ __launch_bounds__(256) void cvt_full(const float* __restrict__ x,
                                                const float* __restrict__ wq,
                                                const float* __restrict__ wk,
                                                const float* __restrict__ wv,
                                                const float* __restrict__ wo,
                                                unsigned short* __restrict__ ws) {
  const size_t n0 = 1048576, n1 = n0 + 2097152, n2 = n1 + 524288, n3 = n2 + 524288, n4 = n3 + 2097152;
  for (size_t c = (size_t)blockIdx.x * 256 + threadIdx.x; c < n4; c += (size_t)gridDim.x * 256) {
    const float* src; unsigned short* dst; size_t off;
    if (c < n0)      { src = x;  dst = ws + WS_XB; off = c; }
    else if (c < n1) { src = wq; dst = ws + WS_WQ; off = c - n0; }
    else if (c < n2) { src = wk; dst = ws + WS_WK; off = c - n1; }
    else if (c < n3) { src = wv; dst = ws + WS_WV; off = c - n2; }
    else             { src = wo; dst = ws + WS_WO; off = c - n3; }
    float4 f0 = ((const float4*)src)[off * 2], f1 = ((const float4*)src)[off * 2 + 1];
    ((bf16x8*)dst)[off] = pack8(f0, f1);
  }
}

// --------------------------------------------------------------------------- tables
__global__ __launch_bounds__(256) void rope_prep(const int* __restrict__ spp,
                                                 float* __restrict__ tab) {
  int idx = blockIdx.x * 256 + threadIdx.x;   // 65536 entries: idx = t*64 + i
  int t = idx >> 6, i = idx & 63;
  float ang = (float)(spp[0] + t) * exp2f(-(float)i * 0.2076205059304602f);
  tab[idx] = sinf(ang);
  tab[65536 + idx] = cosf(ang);
}

// --------------------------------------------------------------------------- old cache -> bf16 KT/VT
__global__ __launch_bounds__(256) void convert_cache(const float* __restrict__ ck,
                                                     const float* __restrict__ cv,
                                                     const int* __restrict__ spp,
                                                     unsigned short* __restrict__ kt,
                                                     unsigned short* __restrict__ vt) {
  const int sp = spp[0];
  const int bk = blockIdx.y;           // b*8+kh
  const int b = bk >> 3, kh = bk & 7;
  const int s1 = blockIdx.x * 128;
  if (s1 >= sp) return;
  const int tid = threadIdx.x;
#pragma unroll
  for (int it = 0; it < 8; ++it) {     // K: 2048 chunks x 8 d
    int c = tid + it * 256;
    int s = c >> 4, dc = (c & 15) * 8;
    if (s1 + s < sp) {
      const float* src = ck + (((size_t)(b * 4096 + s1 + s)) * 8 + kh) * 128 + dc;
      *(bf16x8*)(kt + ((size_t)bk * SMAX + s1 + s) * 128 + dc) = pack8(*(const float4*)src, *(const float4*)(src + 4));
    }
  }
#pragma unroll
  for (int it = 0; it < 8; ++it) {     // V -> VT: 128 d x 16 s-groups of 8
    int c = tid + it * 256;
    int d = c & 127, sg = c >> 7;
    bf16x8 tmp;
#pragma unroll
    for (int ss = 0; ss < 8; ++ss) {
      int s = s1 + sg * 8 + ss;
      tmp[ss] = (s < sp) ? (__bf16)cv[(((size_t)(b * 4096 + s)) * 8 + kh) * 128 + d] : (__bf16)0.0f;
    }
    *(bf16x8*)(vt + (size_t)bk * 128 * SMAX + (size_t)d * SMAX + s1 + sg * 8) = tmp;
  }
}

// --------------------------------------------------------------------------- ring-4 pipelined GEMM
// Proven gemm_core geometry (128x128 tile, 256 thr, 768/512-block grids, natural
// per-XCD B-column locality) + ring-4 LDS (64KB, 2 blocks/CU), counted vmcnt
// (never 0 in steady state), ONE barrier per K-step, validated XOR swizzle pair
// (source-side for DMA, read-side for frags -> 0 bank conflicts), setprio on MFMA.
// EPI 0: fp32 out ldC=4096 (Wo). EPI 1: QKV rope/scatter epilogue.
template<int EPI>
__global__ __launch_bounds__(256) void gemm_r2(const unsigned short* __restrict__ A,
                                               const unsigned short* __restrict__ B,
                                               float* __restrict__ Cout,
                                               unsigned short* __restrict__ qb,
                                               unsigned short* __restrict__ kt,
                                               unsigned short* __restrict__ vt,
                                               const float* __restrict__ tab,
                                               const int* __restrict__ spp) {
  __shared__ __align__(16) unsigned short lds[4 * 8192];   // 4 ring slots x (A 8KB | B 8KB)
  constexpr int K = 4096, NT = 128;
  const int tid = threadIdx.x, lane = tid & 63, wv = tid >> 6;
  const int quad = lane >> 4, l16 = lane & 15;
  const int wm = (wv >> 1) * 64, wn = (wv & 1) * 64;
  const int m0 = blockIdx.y * 128, n0 = blockIdx.x * 128;
  const int sp = spp ? spp[0] : 0;

  floatx4 acc[4][4] = {};

  // staging: chunk c -> row c>>2, phys 16B-slot c&3; SOURCE logical slot (c&3)^((c>>3)&3)
  // (involution matches the read-side swizzle; validated in round-1 gemm8: 0 conflicts)
  const int r0 = tid >> 2, r1 = r0 + 64;
  const int sl = ((tid & 3) ^ ((tid >> 3) & 3)) * 8;
  const unsigned short* a0 = A + (size_t)(m0 + r0) * K + sl;
  const unsigned short* a1 = A + (size_t)(m0 + r1) * K + sl;
  const unsigned short* b0 = B + (size_t)(n0 + r0) * K + sl;
  const unsigned short* b1 = B + (size_t)(n0 + r1) * K + sl;
  const int d0 = tid * 8, d1 = d0 + 2048;          // shorts within A region; B adds 4096

  // frag reads: logical quad at row R lives at phys quad^((R>>1)&3) -> lane-constant XOR
  const int fx = (quad ^ ((l16 >> 1) & 3)) * 8;
  const int abase = (wm + l16) * 32 + fx;
  const int bbase = 4096 + (wn + l16) * 32 + fx;

  auto stage = [&](int t) {
    unsigned short* sb = lds + (t & 3) * 8192;
    const int ko = t * 32;
    gll16(a0 + ko, sb + d0);
    gll16(a1 + ko, sb + d1);
    gll16(b0 + ko, sb + 4096 + d0);
    gll16(b1 + ko, sb + 4096 + d1);
  };

  stage(0); stage(1); stage(2);          // prefetch depth 3 (12 loads in flight)
  for (int t = 0; t < NT; ++t) {
    // drain ONLY tile t's 4 loads; keep up to 8 in flight across the barrier
    if (t + 3 <= NT)      asm volatile("s_waitcnt vmcnt(8)" ::: "memory");
    else if (t + 2 == NT) asm volatile("s_waitcnt vmcnt(4)" ::: "memory");
    else                  asm volatile("s_waitcnt vmcnt(0)" ::: "memory");
    __builtin_amdgcn_s_barrier();          // all waves' stage(t) landed; slot (t-1)&3 free
    __builtin_amdgcn_sched_barrier(0);     // nothing (esp. ds_read) crosses the barrier
    if (t + 3 < NT) stage(t + 3);          // into slot (t-1)&3; overlaps with compute below
    const unsigned short* sb = lds + (t & 3) * 8192;
    bf16x8 af[4], bfr[4];
#pragma unroll
    for (int mi = 0; mi < 4; ++mi)
      af[mi] = *(const bf16x8*)(sb + abase + mi * 512);
#pragma unroll
    for (int ni = 0; ni < 4; ++ni)
      bfr[ni] = *(const bf16x8*)(sb + bbase + ni * 512);
    __builtin_amdgcn_s_setprio(1);
#pragma unroll
    for (int mi = 0; mi < 4; ++mi)
#pragma unroll
      for (int ni = 0; ni < 4; ++ni)
        acc[mi][ni] = __builtin_amdgcn_mfma_f32_16x16x32_bf16(af[mi], bfr[ni], acc[mi][ni], 0, 0, 0);
    __builtin_amdgcn_s_setprio(0);
    asm volatile("s_waitcnt lgkmcnt(0)" ::: "memory");   // my slot-t reads drained
  }

  if constexpr (EPI == 0) {
#pragma unroll
    for (int mi = 0; mi < 4; ++mi)
#pragma unroll
      for (int r = 0; r < 4; ++r) {
        const int row = m0 + wm + mi * 16 + quad * 4 + r;
#pragma unroll
        for (int ni = 0; ni < 4; ++ni)
          Cout[(size_t)row * 4096 + n0 + wn + ni * 16 + l16] = acc[mi][ni][r];
      }
  } else {
    const float S_L2E = 0.12751745f;  // (1/sqrt(128)) * log2(e)
#pragma unroll
    for (int mi = 0; mi < 4; ++mi) {
#pragma unroll
      for (int r = 0; r < 4; ++r) {
        const int row = m0 + wm + mi * 16 + quad * 4 + r;
        const int bb = row >> 10, tt = row & 1023;
#pragma unroll
        for (int ni = 0; ni < 4; ++ni) {
          const int col = n0 + wn + ni * 16 + l16;
          float v = acc[mi][ni][r];
          if (col < 5120) {  // q or k: RoPE (block-uniform outer branch)
            int dd = col & 127, i = dd >> 1;
            float sn = tab[tt * 64 + i], cs = tab[65536 + tt * 64 + i];
            float vp = __shfl_xor(v, 1, 64);
            float o = (dd & 1) ? (vp * sn + v * cs) : (v * cs - vp * sn);
            if (col < 4096) {
              qb[(size_t)row * 4096 + col] = f2bf(o * S_L2E);
            } else {
              int lc = col - 4096, kh = lc >> 7, d = lc & 127;
              kt[((size_t)(bb * 8 + kh) * SMAX + sp + tt) * 128 + d] = f2bf(o);
            }
          } else {
            int lc = col - 5120, kh = lc >> 7, d = lc & 127;
            vt[((size_t)(bb * 8 + kh) * 128 + d) * SMAX + sp + tt] = f2bf(v);
          }
        }
      }
    }
  }
}

// --------------------------------------------------------------------------- old unified GEMM core (fallback path)
template<bool BDMA, int EPI>
__global__ __launch_bounds__(256) void gemm_core(const unsigned short* __restrict__ A,
                                                 const unsigned short* __restrict__ Bb,
                                                 const float* __restrict__ Bq,
                                                 const float* __restrict__ Bk,
                                                 const float* __restrict__ Bv,
                                                 float* __restrict__ Cout,
                                                 unsigned short* __restrict__ qb,
                                                 unsigned short* __restrict__ kt,
                                                 unsigned short* __restrict__ vt,
                                                 const float* __restrict__ tab,
                                                 const int* __restrict__ spp) {
  constexpr int SB = BDMA ? 32 : 40;
  __shared__ __align__(16) unsigned short la[128 * 32];
  __shared__ __align__(16) unsigned short lb[128 * SB];
  const int K = 4096;
  const int tid = threadIdx.x, lane = tid & 63, wv = tid >> 6;
  const int quad = lane >> 4, l16 = lane & 15;
  const int wm = (wv >> 1) * 64, wn = (wv & 1) * 64;
  const int m0 = blockIdx.y * 128, n0 = blockIdx.x * 128;
  const int sp = spp ? spp[0] : 0;

  floatx4 acc[4][4] = {};

  const int r0 = tid >> 2, kc0 = (tid & 3) * 8;
  const int r1 = (tid + 256) >> 2, kc1 = ((tid + 256) & 3) * 8;
  const unsigned short* a0 = A + (size_t)(m0 + r0) * K + kc0;
  const unsigned short* a1 = A + (size_t)(m0 + r1) * K + kc1;

  const unsigned short* bh0 = nullptr; const unsigned short* bh1 = nullptr;
  const float* bf0 = nullptr; const float* bf1 = nullptr;
  if (BDMA) {
    bh0 = Bb + (size_t)(n0 + r0) * K + kc0;
    bh1 = Bb + (size_t)(n0 + r1) * K + kc1;
  } else {
    const float* Bf; int nb;
    if (EPI == 0)      { Bf = Bq; nb = n0; }
    else {
      if (n0 < 4096)      { Bf = Bq; nb = n0; }
      else if (n0 < 5120) { Bf = Bk; nb = n0 - 4096; }
      else                { Bf = Bv; nb = n0 - 5120; }
    }
    bf0 = Bf + (size_t)(nb + r0) * K + kc0;
    bf1 = Bf + (size_t)(nb + r1) * K + kc1;
  }

  for (int k0 = 0; k0 < K; k0 += 32) {
    gll16(a0 + k0, la + tid * 8);
    gll16(a1 + k0, la + (tid + 256) * 8);
    if (BDMA) {
      gll16(bh0 + k0, lb + tid * 8);
      gll16(bh1 + k0, lb + (tid + 256) * 8);
    } else {
      bf16x8 vb0 = pack8(*(const float4*)(bf0 + k0), *(const float4*)(bf0 + k0 + 4));
      bf16x8 vb1 = pack8(*(const float4*)(bf1 + k0), *(const float4*)(bf1 + k0 + 4));
      *(bf16x8*)(lb + r0 * 40 + kc0) = vb0;
      *(bf16x8*)(lb + r1 * 40 + kc1) = vb1;
    }
    __syncthreads();
    bf16x8 af[4], bfr[4];
#pragma unroll
    for (int mi = 0; mi < 4; ++mi)
      af[mi] = *(const bf16x8*)(la + (wm + mi * 16 + l16) * 32 + quad * 8);
#pragma unroll
    for (int ni = 0; ni < 4; ++ni)
      bfr[ni] = *(const bf16x8*)(lb + (wn + ni * 16 + l16) * SB + quad * 8);
#pragma unroll
    for (int mi = 0; mi < 4; ++mi)
#pragma unroll
      for (int ni = 0; ni < 4; ++ni)
        acc[mi][ni] = __builtin_amdgcn_mfma_f32_16x16x32_bf16(af[mi], bfr[ni], acc[mi][ni], 0, 0, 0);
    __syncthreads();
  }

  if (EPI == 0) {
#pragma unroll
    for (int mi = 0; mi < 4; ++mi)
#pragma unroll
      for (int r = 0; r < 4; ++r) {
        const int row = m0 + wm + mi * 16 + quad * 4 + r;
#pragma unroll
        for (int ni = 0; ni < 4; ++ni)
          Cout[(size_t)row * 4096 + n0 + wn + ni * 16 + l16] = acc[mi][ni][r];
      }
  } else {
    const float S_L2E = 0.12751745f;
#pragma unroll
    for (int mi = 0; mi < 4; ++mi) {
#pragma unroll
      for (int r = 0; r < 4; ++r) {
        const int row = m0 + wm + mi * 16 + quad * 4 + r;
        const int b = row >> 10, t = row & 1023;
#pragma unroll
        for (int ni = 0; ni < 4; ++ni) {
          const int col = n0 + wn + ni * 16 + l16;
          float v = acc[mi][ni][r];
          if (col < 5120) {
            int dd = col & 127, i = dd >> 1;
            float sn = tab[t * 64 + i], cs = tab[65536 + t * 64 + i];
            float vp = __shfl_xor(v, 1, 64);
            float o = (dd & 1) ? (vp * sn + v * cs) : (v * cs - vp * sn);
            if (col < 4096) {
              qb[(size_t)row * 4096 + col] = f2bf(o * S_L2E);
            } else {
              int lc = col - 4096, kh = lc >> 7, d = lc & 127;
              kt[((size_t)(b * 8 + kh) * SMAX + sp + t) * 128 + d] = f2bf(o);
            }
          } else {
            int lc = col - 5120, kh = lc >> 7, d = lc & 127;
            vt[((size_t)(b * 8 + kh) * 128 + d) * SMAX + sp + t] = f2bf(v);
          }
        }
      }
    }
  }
}

// --------------------------------------------------------------------------- flash attention (round-1, proven)
__global__ __launch_bounds__(512, 2) void attn(const unsigned short* __restrict__ qb,
                                               const unsigned short* __restrict__ ktg,
                                               const unsigned short* __restrict__ vtg,
                                               const int* __restrict__ spp,
                                               unsigned short* __restrict__ ctx) {
  __shared__ __align__(16) unsigned short lds[32768];

  const int sp = spp[0];
  const int iblk = (int)blockIdx.y * 4 + (int)blockIdx.x;
  const int lblk = (iblk & 7) * 32 + (iblk >> 3);
  const int x = lblk & 3, bh = lblk >> 2;
  const int b = bh >> 5, h = bh & 31;
  const int bk = b * 8 + (h >> 2);
  const int tid = threadIdx.x, lane = tid & 63, w = tid >> 6;
  const int hi = lane >> 5, l31 = lane & 31;
  const int tq128 = (w < 4) ? x : (7 - x);
  const int wq0 = tq128 * 128 + (w & 3) * 32;
  const int q = wq0 + l31;
  const int lim = sp + q;
  const int wlim = sp + wq0 + 31;
  const int nt = (sp + (8 - x) * 128 + 63) >> 6;

  const unsigned short* ktb = ktg + (size_t)bk * SMAX * 128;
  const unsigned short* vtb = vtg + (size_t)bk * 128 * SMAX;

  const int kr0 = tid >> 4, kc = tid & 15, kr1 = kr0 + 32;
  const int ksl0 = ((kc ^ (kr0 & 15)) << 3), ksl1 = ((kc ^ (kr1 & 15)) << 3);
  const int vd0 = tid >> 3, vc = tid & 7, vd1 = vd0 + 64;
  const int vsl0 = ((vc ^ (vd0 & 7)) << 3), vsl1 = ((vc ^ (vd1 & 7)) << 3);

  bf16x8 qf[8];
  {
    const unsigned short* qbase = qb + ((size_t)(b * 1024 + q)) * 4096 + h * 128 + hi * 8;
#pragma unroll
    for (int kg = 0; kg < 8; ++kg) qf[kg] = *(const bf16x8*)(qbase + kg * 16);
  }

  floatx16 oacc[4] = {};
  float mrun = -1e30f, lrun = 0.0f;

  *(bf16x8*)(lds + kr0 * 128 + ksl0)         = *(const bf16x8*)(ktb + (size_t)kr0 * 128 + kc * 8);
  *(bf16x8*)(lds + kr1 * 128 + ksl1)         = *(const bf16x8*)(ktb + (size_t)kr1 * 128 + kc * 8);
  *(bf16x8*)(lds + 16384 + vd0 * 64 + vsl0)  = *(const bf16x8*)(vtb + (size_t)vd0 * SMAX + vc * 8);
  *(bf16x8*)(lds + 16384 + vd1 * 64 + vsl1)  = *(const bf16x8*)(vtb + (size_t)vd1 * SMAX + vc * 8);
  __syncthreads();

  int off = 0;
  for (int st = 0; st < nt; ++st) {
    const int s0 = st * 64;
    bf16x8 nk0, nk1, nv0, nv1;
    const bool pre = (st + 1 < nt);
    if (pre) {
      const int s1 = s0 + 64;
      nk0 = *(const bf16x8*)(ktb + (size_t)(s1 + kr0) * 128 + kc * 8);
      nk1 = *(const bf16x8*)(ktb + (size_t)(s1 + kr1) * 128 + kc * 8);
      nv0 = *(const bf16x8*)(vtb + (size_t)vd0 * SMAX + s1 + vc * 8);
      nv1 = *(const bf16x8*)(vtb + (size_t)vd1 * SMAX + s1 + vc * 8);
      asm volatile("" ::: "memory");
    }
    const unsigned short* kl = lds + off;
    const unsigned short* vl = lds + 16384 + off;
    if (s0 <= wlim) {
#pragma unroll
      for (int sub = 0; sub < 2; ++sub) {
        const int ss = s0 + sub * 32;
        if (ss <= wlim) {
          floatx16 sa = {0,0,0,0,0,0,0,0,0,0,0,0,0,0,0,0};
          const unsigned short* kbase = kl + (sub * 32 + l31) * 128;
          const int kx = l31 & 15;
#pragma unroll
          for (int kg = 0; kg < 8; ++kg) {
            bf16x8 kf = *(const bf16x8*)(kbase + (((kg * 2 + hi) ^ kx) << 3));
            sa = __builtin_amdgcn_mfma_f32_32x32x16_bf16(kf, qf[kg], sa, 0, 0, 0);
          }
          if (ss + 31 > sp + wq0) {
#pragma unroll
            for (int r = 0; r < 16; ++r) {
              const int j = ss + (r & 3) + 8 * (r >> 2) + 4 * hi;
              if (j > lim) sa[r] = -1e30f;
            }
          }
          float mt = sa[0];
#pragma unroll
          for (int r = 1; r < 16; ++r) mt = fmaxf(mt, sa[r]);
          mt = fmaxf(mt, __shfl_xor(mt, 32, 64));
          if (!__all(mt <= mrun + 8.0f)) {
            const float mnew = fmaxf(mrun, mt);
            const float al = exp2f(mrun - mnew);
#pragma unroll
            for (int db = 0; db < 4; ++db)
#pragma unroll
              for (int r = 0; r < 16; ++r) oacc[db][r] *= al;
            lrun *= al;
            mrun = mnew;
          }
          float p[16]; float ls = 0.0f;
#pragma unroll
          for (int r = 0; r < 16; ++r) { p[r] = exp2f(sa[r] - mrun); ls += p[r]; }
          lrun += ls + __shfl_xor(ls, 32, 64);
#pragma unroll
          for (int ks = 0; ks < 2; ++ks) {
            const int rb = ks * 8;
            unsigned a0 = cvtpk_bf16(p[rb + 0], p[rb + 1]);
            unsigned a1 = cvtpk_bf16(p[rb + 2], p[rb + 3]);
            unsigned b0 = cvtpk_bf16(p[rb + 4], p[rb + 5]);
            unsigned b1 = cvtpk_bf16(p[rb + 6], p[rb + 7]);
            const unsigned t0 = __shfl_xor(a0, 32, 64);
            const unsigned t1 = __shfl_xor(b0, 32, 64);
            const unsigned t2 = __shfl_xor(a1, 32, 64);
            const unsigned t3 = __shfl_xor(b1, 32, 64);
            union { unsigned u[4]; bf16x8 v; } pf;
            pf.u[0] = hi ? t1 : a0;
            pf.u[1] = hi ? t3 : a1;
            pf.u[2] = hi ? b0 : t0;
            pf.u[3] = hi ? b1 : t2;
            const int sslot = sub * 4 + ks * 2 + hi;
#pragma unroll
            for (int db = 0; db < 4; ++db) {
              const int vrow = db * 32 + l31;
              bf16x8 vf = *(const bf16x8*)(vl + vrow * 64 + ((sslot ^ (l31 & 7)) << 3));
              oacc[db] = __builtin_amdgcn_mfma_f32_32x32x16_bf16(vf, pf.v, oacc[db], 0, 0, 0);
            }
          }
        }
      }
    }
    if (pre) {
      unsigned short* kn = lds + (off ^ 8192);
      unsigned short* vn = lds + 16384 + (off ^ 8192);
      *(bf16x8*)(kn + kr0 * 128 + ksl0) = nk0;
      *(bf16x8*)(kn + kr1 * 128 + ksl1) = nk1;
      *(bf16x8*)(vn + vd0 * 64 + vsl0) = nv0;
      *(bf16x8*)(vn + vd1 * 64 + vsl1) = nv1;
    }
    __syncthreads();
    off ^= 8192;
  }

  const float invl = 1.0f / lrun;
  unsigned short* myo = lds + w * 4096;
#pragma unroll
  for (int db = 0; db < 4; ++db)
#pragma unroll
    for (int i2 = 0; i2 < 8; ++i2) {
      const int r = i2 * 2;
      const int d = db * 32 + (r & 3) + 8 * (r >> 2) + 4 * hi;
      const unsigned wo = cvtpk_bf16(oacc[db][r] * invl, oacc[db][r + 1] * invl);
      *(unsigned*)(myo + l31 * 128 + (((2 * d) ^ ((l31 & 15) << 4)) >> 1)) = wo;
    }
  __syncthreads();
#pragma unroll
  for (int it = 0; it < 8; ++it) {
    const int c = tid + it * 512;
    const int wr = c >> 9, row = (c >> 4) & 31, c16 = c & 15;
    const int tq = (((wr < 4) ? x : (7 - x)) * 128) + (wr & 3) * 32 + row;
    bf16x8 vv = *(const bf16x8*)(lds + wr * 4096 + row * 128 + ((c16 ^ (row & 15)) << 3));
    *(bf16x8*)(ctx + ((size_t)(b * 1024 + tq)) * 4096 + h * 128 + c16 * 8) = vv;
  }
}

// ---------------------------------------------------------------------------
extern "C" void kernel_launch(void* const* d_in, const int* in_sizes, int n_in,
                              void* d_out, int out_size, void* d_ws, size_t ws_size,
                              hipStream_t stream) {
  const float* x  = (const float*)d_in[0];
  const int* sp   = (const int*)d_in[1];
  float* ck       = (float*)d_in[2];
  const float* cv = (const float*)d_in[3];
  const float* Wq = (const float*)d_in[4];
  const float* Wk = (const float*)d_in[5];
  const float* Wv = (const float*)d_in[6];
  const float* Wo = (const float*)d_in[7];
  float* out      = (float*)d_out;

  unsigned short* qb  = (unsigned short*)d_out;
  unsigned short* kt  = (unsigned short*)d_out + KT_OFF;
  unsigned short* vt  = (unsigned short*)d_out + VT_OFF;
  unsigned short* ws  = (unsigned short*)d_ws;
  unsigned short* xb  = ws + WS_XB;                 // shares [0,16.8MB) with ctx (disjoint lifetime)
  unsigned short* ctx = ws + WS_XB;
  float* tab          = ck + (size_t)2048 * 1024;   // unused cache_keys tail

  const bool full = ws_size >= WS_FULL_BYTES;

  rope_prep<<<256, 256, 0, stream>>>(sp, tab);
  convert_cache<<<dim3(16, 16), 256, 0, stream>>>(ck, cv, sp, kt, vt);

  if (full) {
    cvt_full<<<2048, 256, 0, stream>>>(x, Wq, Wk, Wv, Wo, ws);
    gemm_r2<1><<<dim3(48, 16), 256, 0, stream>>>(xb, ws + WS_WQ, nullptr, qb, kt, vt, tab, sp);
    attn<<<dim3(4, 64), 512, 0, stream>>>(qb, kt, vt, sp, ctx);
    gemm_r2<0><<<dim3(32, 16), 256, 0, stream>>>(ctx, ws + WS_WO, out, nullptr, nullptr, nullptr,
                                                 nullptr, nullptr);
  } else {
    cvt_x<<<2048, 256, 0, stream>>>(x, xb);
    gemm_core<false, 1><<<dim3(48, 16), 256, 0, stream>>>(xb, nullptr, Wq, Wk, Wv,
                                                          nullptr, qb, kt, vt, tab, sp);
    attn<<<dim3(4, 64), 512, 0, stream>>>(qb, kt, vt, sp, ctx);
    gemm_core<false, 0><<<dim3(32, 16), 256, 0, stream>>>(ctx, nullptr, Wo, nullptr, nullptr,
                                                          out, nullptr, nullptr, nullptr, nullptr, nullptr);
  }
}

// Round 4
// 566.360 us; speedup vs baseline: 1.1155x; 1.0769x over previous
//
#include <hip/hip_runtime.h>
#include <math.h>

// B=2, T=1024, C=4096, Hq=32, Hkv=8, D=128, G=4; start_pos on device (1024).
// I/O fp32; compute bf16 MFMA. d_out doubles as bf16 scratch before the final GEMM:
//   [0 .. 16.8MB)  qb   bf16 [b*1024+t][4096]   (q, RoPE'd, pre-scaled by 1/sqrt(D)*log2e)
//   [16.8 .. 25.2) KT   bf16 [b][kh][s<2048][d]
//   [25.2 .. 33.5) VT   bf16 [b][kh][d][s<2048]
// ws layout unchanged (full: bf16 weights; fallback: fp32 weights, old gemm path).

typedef __bf16 bf16x8 __attribute__((ext_vector_type(8)));
typedef float floatx4 __attribute__((ext_vector_type(4)));
typedef float floatx16 __attribute__((ext_vector_type(16)));

constexpr int SMAX = 2048;
constexpr size_t KT_OFF = (size_t)2 * 1024 * 4096;             // shorts
constexpr size_t VT_OFF = KT_OFF + (size_t)2 * 8 * SMAX * 128;
// ws offsets in shorts
constexpr size_t WS_XB = 0;
constexpr size_t WS_WQ = 8388608;
constexpr size_t WS_WK = 25165824;
constexpr size_t WS_WV = 29360128;
constexpr size_t WS_WO = 33554432;
constexpr size_t WS_FULL_BYTES = 100663296;

__device__ __forceinline__ unsigned short f2bf(float f) {
  union { float f; unsigned int u; } v; v.f = f;
  unsigned int u = v.u;
  return (unsigned short)((u + 0x7fffu + ((u >> 16) & 1u)) >> 16);
}

__device__ __forceinline__ bf16x8 pack8(float4 a, float4 b) {
  bf16x8 v;
  v[0] = (__bf16)a.x; v[1] = (__bf16)a.y; v[2] = (__bf16)a.z; v[3] = (__bf16)a.w;
  v[4] = (__bf16)b.x; v[5] = (__bf16)b.y; v[6] = (__bf16)b.z; v[7] = (__bf16)b.w;
  return v;
}

__device__ __forceinline__ unsigned cvtpk_bf16(float lo, float hi) {
  unsigned r;
  asm("v_cvt_pk_bf16_f32 %0, %1, %2" : "=v"(r) : "v"(lo), "v"(hi));
  return r;
}

// async global(16B/lane) -> LDS DMA; dest = wave-uniform base + lane*16
__device__ __forceinline__ void gll16(const unsigned short* g, unsigned short* l) {
  __builtin_amdgcn_global_load_lds((const __attribute__((address_space(1))) void*)g,
                                   (__attribute__((address_space(3))) void*)l, 16, 0, 0);
}

// --------------------------------------------------------------------------- fp32 -> bf16 converters
__global__ __launch_bounds__(256) void cvt_x(const float* __restrict__ x,
                                             unsigned short* __restrict__ xb) {
  for (size_t c = (size_t)blockIdx.x * 256 + threadIdx.x; c < 1048576; c += (size_t)gridDim.x * 256) {
    float4 f0 = ((const float4*)x)[c * 2], f1 = ((const float4*)x)[c * 2 + 1];
    ((bf16x8*)xb)[c] = pack8(f0, f1);
  }
}

__global__ __launch_bounds__(256) void cvt_full(const float* __restrict__ x,
                                                const float* __restrict__ wq,
                                                const float* __restrict__ wk,
                                                const float* __restrict__ wv,
                                                const float* __restrict__ wo,
                                                unsigned short* __restrict__ ws) {
  const size_t n0 = 1048576, n1 = n0 + 2097152, n2 = n1 + 524288, n3 = n2 + 524288, n4 = n3 + 2097152;
  for (size_t c = (size_t)blockIdx.x * 256 + threadIdx.x; c < n4; c += (size_t)gridDim.x * 256) {
    const float* src; unsigned short* dst; size_t off;
    if (c < n0)      { src = x;  dst = ws + WS_XB; off = c; }
    else if (c < n1) { src = wq; dst = ws + WS_WQ; off = c - n0; }
    else if (c < n2) { src = wk; dst = ws + WS_WK; off = c - n1; }
    else if (c < n3) { src = wv; dst = ws + WS_WV; off = c - n2; }
    else             { src = wo; dst = ws + WS_WO; off = c - n3; }
    float4 f0 = ((const float4*)src)[off * 2], f1 = ((const float4*)src)[off * 2 + 1];
    ((bf16x8*)dst)[off] = pack8(f0, f1);
  }
}

// --------------------------------------------------------------------------- tables
__global__ __launch_bounds__(256) void rope_prep(const int* __restrict__ spp,
                                                 float* __restrict__ tab) {
  int idx = blockIdx.x * 256 + threadIdx.x;   // 65536 entries: idx = t*64 + i
  int t = idx >> 6, i = idx & 63;
  float ang = (float)(spp[0] + t) * exp2f(-(float)i * 0.2076205059304602f);
  tab[idx] = sinf(ang);
  tab[65536 + idx] = cosf(ang);
}

// --------------------------------------------------------------------------- old cache -> bf16 KT/VT
__global__ __launch_bounds__(256) void convert_cache(const float* __restrict__ ck,
                                                     const float* __restrict__ cv,
                                                     const int* __restrict__ spp,
                                                     unsigned short* __restrict__ kt,
                                                     unsigned short* __restrict__ vt) {
  const int sp = spp[0];
  const int bk = blockIdx.y;           // b*8+kh
  const int b = bk >> 3, kh = bk & 7;
  const int s1 = blockIdx.x * 128;
  if (s1 >= sp) return;
  const int tid = threadIdx.x;
#pragma unroll
  for (int it = 0; it < 8; ++it) {     // K: 2048 chunks x 8 d
    int c = tid + it * 256;
    int s = c >> 4, dc = (c & 15) * 8;
    if (s1 + s < sp) {
      const float* src = ck + (((size_t)(b * 4096 + s1 + s)) * 8 + kh) * 128 + dc;
      *(bf16x8*)(kt + ((size_t)bk * SMAX + s1 + s) * 128 + dc) = pack8(*(const float4*)src, *(const float4*)(src + 4));
    }
  }
#pragma unroll
  for (int it = 0; it < 8; ++it) {     // V -> VT: 128 d x 16 s-groups of 8
    int c = tid + it * 256;
    int d = c & 127, sg = c >> 7;
    bf16x8 tmp;
#pragma unroll
    for (int ss = 0; ss < 8; ++ss) {
      int s = s1 + sg * 8 + ss;
      tmp[ss] = (s < sp) ? (__bf16)cv[(((size_t)(b * 4096 + s)) * 8 + kh) * 128 + d] : (__bf16)0.0f;
    }
    *(bf16x8*)(vt + (size_t)bk * 128 * SMAX + (size_t)d * SMAX + s1 + sg * 8) = tmp;
  }
}

// --------------------------------------------------------------------------- ring-4 pipelined GEMM
// C[m][n] = sum_k A[m][k]*B[n][k]; A,B bf16 row-major K=4096. Tile 128 x BN.
// Ring-4 LDS slots (BK=32), counted vmcnt (never 0 in steady state), ONE barrier
// per K-step, validated XOR swizzle pair (source-side for DMA, read-side for
// frags -> 0 bank conflicts), setprio on MFMA. Grid MUST be a multiple of 256
// blocks for CU balance (the round-2/3 lesson): QKV uses BN=192 -> 512 blocks
// (80KB LDS ring, 2 blocks/CU = 160KB exact); Wo uses BN=128 -> 512 blocks.
// EPI 0: fp32 out ldC=4096 (Wo). EPI 1: QKV rope/scatter epilogue.
template<int EPI, int BN>
__global__ __launch_bounds__(256) void gemm_r2(const unsigned short* __restrict__ A,
                                               const unsigned short* __restrict__ B,
                                               float* __restrict__ Cout,
                                               unsigned short* __restrict__ qb,
                                               unsigned short* __restrict__ kt,
                                               unsigned short* __restrict__ vt,
                                               const float* __restrict__ tab,
                                               const int* __restrict__ spp) {
  constexpr int SLOT = 4096 + BN * 32;        // shorts per ring slot (A 8KB | B BN*64B)
  constexpr int BL = BN / 64;                 // B staging loads per thread (2 or 3)
  constexpr int NI = BN / 32;                 // B frag count per wave (4 or 6)
  __shared__ __align__(16) unsigned short lds[4 * SLOT];
  constexpr int K = 4096, NT = 128;
  const int tid = threadIdx.x, lane = tid & 63, wv = tid >> 6;
  const int quad = lane >> 4, l16 = lane & 15;
  const int wm = (wv >> 1) * 64, wn = (wv & 1) * (BN / 2);
  const int m0 = blockIdx.y * 128, n0 = blockIdx.x * BN;
  const int sp = spp ? spp[0] : 0;

  floatx4 acc[4][NI] = {};

  // staging: chunk c -> row c>>2, phys 16B-slot c&3; SOURCE logical slot (c&3)^((c>>3)&3)
  // (involution matches the read-side swizzle; validated rounds 1-3: 0 conflicts)
  const int r0 = tid >> 2;
  const int sl = ((tid & 3) ^ ((tid >> 3) & 3)) * 8;
  const unsigned short* a0 = A + (size_t)(m0 + r0) * K + sl;
  const unsigned short* a1 = A + (size_t)(m0 + r0 + 64) * K + sl;
  const unsigned short* b0 = B + (size_t)(n0 + r0) * K + sl;
  const unsigned short* b1 = B + (size_t)(n0 + r0 + 64) * K + sl;
  const unsigned short* b2 = (BL == 3) ? B + (size_t)(n0 + r0 + 128) * K + sl : nullptr;
  const int d0 = tid * 8;                     // shorts within A region; B adds 4096

  // frag reads: logical quad at row R lives at phys quad^((R>>1)&3) -> lane-constant XOR
  const int fx = (quad ^ ((l16 >> 1) & 3)) * 8;
  const int abase = (wm + l16) * 32 + fx;
  const int bbase = 4096 + (wn + l16) * 32 + fx;

  auto stage = [&](int t) {
    unsigned short* sb = lds + (t & 3) * SLOT;
    const int ko = t * 32;
    gll16(a0 + ko, sb + d0);
    gll16(a1 + ko, sb + d0 + 2048);
    gll16(b0 + ko, sb + 4096 + d0);
    gll16(b1 + ko, sb + 4096 + d0 + 2048);
    if constexpr (BL == 3) gll16(b2 + ko, sb + 4096 + d0 + 4096);
  };

  stage(0); stage(1); stage(2);          // prefetch depth 3 (3*(2+BL) loads in flight)
  for (int t = 0; t < NT; ++t) {
    // drain ONLY tile t's loads; keep 2 tiles' worth in flight across the barrier
    if (t + 3 <= NT) {
      if constexpr (BL == 3) asm volatile("s_waitcnt vmcnt(10)" ::: "memory");
      else                   asm volatile("s_waitcnt vmcnt(8)" ::: "memory");
    } else if (t + 2 == NT) {
      if constexpr (BL == 3) asm volatile("s_waitcnt vmcnt(5)" ::: "memory");
      else                   asm volatile("s_waitcnt vmcnt(4)" ::: "memory");
    } else {
      asm volatile("s_waitcnt vmcnt(0)" ::: "memory");
    }
    __builtin_amdgcn_s_barrier();          // all waves' stage(t) landed; slot (t-1)&3 free
    __builtin_amdgcn_sched_barrier(0);     // nothing (esp. ds_read) crosses the barrier
    if (t + 3 < NT) stage(t + 3);          // into slot (t-1)&3; overlaps with compute below
    const unsigned short* sb = lds + (t & 3) * SLOT;
    bf16x8 af[4], bfr[NI];
#pragma unroll
    for (int mi = 0; mi < 4; ++mi)
      af[mi] = *(const bf16x8*)(sb + abase + mi * 512);
#pragma unroll
    for (int ni = 0; ni < NI; ++ni)
      bfr[ni] = *(const bf16x8*)(sb + bbase + ni * 512);
    __builtin_amdgcn_s_setprio(1);
#pragma unroll
    for (int mi = 0; mi < 4; ++mi)
#pragma unroll
      for (int ni = 0; ni < NI; ++ni)
        acc[mi][ni] = __builtin_amdgcn_mfma_f32_16x16x32_bf16(af[mi], bfr[ni], acc[mi][ni], 0, 0, 0);
    __builtin_amdgcn_s_setprio(0);
    asm volatile("s_waitcnt lgkmcnt(0)" ::: "memory");   // my slot-t reads drained
  }

  if constexpr (EPI == 0) {
#pragma unroll
    for (int mi = 0; mi < 4; ++mi)
#pragma unroll
      for (int r = 0; r < 4; ++r) {
        const int row = m0 + wm + mi * 16 + quad * 4 + r;
#pragma unroll
        for (int ni = 0; ni < NI; ++ni)
          Cout[(size_t)row * 4096 + n0 + wn + ni * 16 + l16] = acc[mi][ni][r];
      }
  } else {
    const float S_L2E = 0.12751745f;  // (1/sqrt(128)) * log2(e)
#pragma unroll
    for (int mi = 0; mi < 4; ++mi) {
#pragma unroll
      for (int r = 0; r < 4; ++r) {
        const int row = m0 + wm + mi * 16 + quad * 4 + r;
        const int bb = row >> 10, tt = row & 1023;
#pragma unroll
        for (int ni = 0; ni < NI; ++ni) {
          const int col = n0 + wn + ni * 16 + l16;
          float v = acc[mi][ni][r];
          if (col < 5120) {  // q or k: RoPE (boundary tiles diverge; 2 of 32 only)
            int dd = col & 127, i = dd >> 1;
            float sn = tab[tt * 64 + i], cs = tab[65536 + tt * 64 + i];
            float vp = __shfl_xor(v, 1, 64);
            float o = (dd & 1) ? (vp * sn + v * cs) : (v * cs - vp * sn);
            if (col < 4096) {
              qb[(size_t)row * 4096 + col] = f2bf(o * S_L2E);
            } else {
              int lc = col - 4096, kh = lc >> 7, d = lc & 127;
              kt[((size_t)(bb * 8 + kh) * SMAX + sp + tt) * 128 + d] = f2bf(o);
            }
          } else {
            int lc = col - 5120, kh = lc >> 7, d = lc & 127;
            vt[((size_t)(bb * 8 + kh) * 128 + d) * SMAX + sp + tt] = f2bf(v);
          }
        }
      }
    }
  }
}

// --------------------------------------------------------------------------- old unified GEMM core (fallback path)
template<bool BDMA, int EPI>
__global__ __launch_bounds__(256) void gemm_core(const unsigned short* __restrict__ A,
                                                 const unsigned short* __restrict__ Bb,
                                                 const float* __restrict__ Bq,
                                                 const float* __restrict__ Bk,
                                                 const float* __restrict__ Bv,
                                                 float* __restrict__ Cout,
                                                 unsigned short* __restrict__ qb,
                                                 unsigned short* __restrict__ kt,
                                                 unsigned short* __restrict__ vt,
                                                 const float* __restrict__ tab,
                                                 const int* __restrict__ spp) {
  constexpr int SB = BDMA ? 32 : 40;
  __shared__ __align__(16) unsigned short la[128 * 32];
  __shared__ __align__(16) unsigned short lb[128 * SB];
  const int K = 4096;
  const int tid = threadIdx.x, lane = tid & 63, wv = tid >> 6;
  const int quad = lane >> 4, l16 = lane & 15;
  const int wm = (wv >> 1) * 64, wn = (wv & 1) * 64;
  const int m0 = blockIdx.y * 128, n0 = blockIdx.x * 128;
  const int sp = spp ? spp[0] : 0;

  floatx4 acc[4][4] = {};

  const int r0 = tid >> 2, kc0 = (tid & 3) * 8;
  const int r1 = (tid + 256) >> 2, kc1 = ((tid + 256) & 3) * 8;
  const unsigned short* a0 = A + (size_t)(m0 + r0) * K + kc0;
  const unsigned short* a1 = A + (size_t)(m0 + r1) * K + kc1;

  const unsigned short* bh0 = nullptr; const unsigned short* bh1 = nullptr;
  const float* bf0 = nullptr; const float* bf1 = nullptr;
  if (BDMA) {
    bh0 = Bb + (size_t)(n0 + r0) * K + kc0;
    bh1 = Bb + (size_t)(n0 + r1) * K + kc1;
  } else {
    const float* Bf; int nb;
    if (EPI == 0)      { Bf = Bq; nb = n0; }
    else {
      if (n0 < 4096)      { Bf = Bq; nb = n0; }
      else if (n0 < 5120) { Bf = Bk; nb = n0 - 4096; }
      else                { Bf = Bv; nb = n0 - 5120; }
    }
    bf0 = Bf + (size_t)(nb + r0) * K + kc0;
    bf1 = Bf + (size_t)(nb + r1) * K + kc1;
  }

  for (int k0 = 0; k0 < K; k0 += 32) {
    gll16(a0 + k0, la + tid * 8);
    gll16(a1 + k0, la + (tid + 256) * 8);
    if (BDMA) {
      gll16(bh0 + k0, lb + tid * 8);
      gll16(bh1 + k0, lb + (tid + 256) * 8);
    } else {
      bf16x8 vb0 = pack8(*(const float4*)(bf0 + k0), *(const float4*)(bf0 + k0 + 4));
      bf16x8 vb1 = pack8(*(const float4*)(bf1 + k0), *(const float4*)(bf1 + k0 + 4));
      *(bf16x8*)(lb + r0 * 40 + kc0) = vb0;
      *(bf16x8*)(lb + r1 * 40 + kc1) = vb1;
    }
    __syncthreads();
    bf16x8 af[4], bfr[4];
#pragma unroll
    for (int mi = 0; mi < 4; ++mi)
      af[mi] = *(const bf16x8*)(la + (wm + mi * 16 + l16) * 32 + quad * 8);
#pragma unroll
    for (int ni = 0; ni < 4; ++ni)
      bfr[ni] = *(const bf16x8*)(lb + (wn + ni * 16 + l16) * SB + quad * 8);
#pragma unroll
    for (int mi = 0; mi < 4; ++mi)
#pragma unroll
      for (int ni = 0; ni < 4; ++ni)
        acc[mi][ni] = __builtin_amdgcn_mfma_f32_16x16x32_bf16(af[mi], bfr[ni], acc[mi][ni], 0, 0, 0);
    __syncthreads();
  }

  if (EPI == 0) {
#pragma unroll
    for (int mi = 0; mi < 4; ++mi)
#pragma unroll
      for (int r = 0; r < 4; ++r) {
        const int row = m0 + wm + mi * 16 + quad * 4 + r;
#pragma unroll
        for (int ni = 0; ni < 4; ++ni)
          Cout[(size_t)row * 4096 + n0 + wn + ni * 16 + l16] = acc[mi][ni][r];
      }
  } else {
    const float S_L2E = 0.12751745f;
#pragma unroll
    for (int mi = 0; mi < 4; ++mi) {
#pragma unroll
      for (int r = 0; r < 4; ++r) {
        const int row = m0 + wm + mi * 16 + quad * 4 + r;
        const int b = row >> 10, t = row & 1023;
#pragma unroll
        for (int ni = 0; ni < 4; ++ni) {
          const int col = n0 + wn + ni * 16 + l16;
          float v = acc[mi][ni][r];
          if (col < 5120) {
            int dd = col & 127, i = dd >> 1;
            float sn = tab[t * 64 + i], cs = tab[65536 + t * 64 + i];
            float vp = __shfl_xor(v, 1, 64);
            float o = (dd & 1) ? (vp * sn + v * cs) : (v * cs - vp * sn);
            if (col < 4096) {
              qb[(size_t)row * 4096 + col] = f2bf(o * S_L2E);
            } else {
              int lc = col - 4096, kh = lc >> 7, d = lc & 127;
              kt[((size_t)(b * 8 + kh) * SMAX + sp + t) * 128 + d] = f2bf(o);
            }
          } else {
            int lc = col - 5120, kh = lc >> 7, d = lc & 127;
            vt[((size_t)(b * 8 + kh) * 128 + d) * SMAX + sp + t] = f2bf(v);
          }
        }
      }
    }
  }
}

// --------------------------------------------------------------------------- flash attention (round-1, proven)
__global__ __launch_bounds__(512, 2) void attn(const unsigned short* __restrict__ qb,
                                               const unsigned short* __restrict__ ktg,
                                               const unsigned short* __restrict__ vtg,
                                               const int* __restrict__ spp,
                                               unsigned short* __restrict__ ctx) {
  __shared__ __align__(16) unsigned short lds[32768];

  const int sp = spp[0];
  const int iblk = (int)blockIdx.y * 4 + (int)blockIdx.x;
  const int lblk = (iblk & 7) * 32 + (iblk >> 3);
  const int x = lblk & 3, bh = lblk >> 2;
  const int b = bh >> 5, h = bh & 31;
  const int bk = b * 8 + (h >> 2);
  const int tid = threadIdx.x, lane = tid & 63, w = tid >> 6;
  const int hi = lane >> 5, l31 = lane & 31;
  const int tq128 = (w < 4) ? x : (7 - x);
  const int wq0 = tq128 * 128 + (w & 3) * 32;
  const int q = wq0 + l31;
  const int lim = sp + q;
  const int wlim = sp + wq0 + 31;
  const int nt = (sp + (8 - x) * 128 + 63) >> 6;

  const unsigned short* ktb = ktg + (size_t)bk * SMAX * 128;
  const unsigned short* vtb = vtg + (size_t)bk * 128 * SMAX;

  const int kr0 = tid >> 4, kc = tid & 15, kr1 = kr0 + 32;
  const int ksl0 = ((kc ^ (kr0 & 15)) << 3), ksl1 = ((kc ^ (kr1 & 15)) << 3);
  const int vd0 = tid >> 3, vc = tid & 7, vd1 = vd0 + 64;
  const int vsl0 = ((vc ^ (vd0 & 7)) << 3), vsl1 = ((vc ^ (vd1 & 7)) << 3);

  bf16x8 qf[8];
  {
    const unsigned short* qbase = qb + ((size_t)(b * 1024 + q)) * 4096 + h * 128 + hi * 8;
#pragma unroll
    for (int kg = 0; kg < 8; ++kg) qf[kg] = *(const bf16x8*)(qbase + kg * 16);
  }

  floatx16 oacc[4] = {};
  float mrun = -1e30f, lrun = 0.0f;

  *(bf16x8*)(lds + kr0 * 128 + ksl0)         = *(const bf16x8*)(ktb + (size_t)kr0 * 128 + kc * 8);
  *(bf16x8*)(lds + kr1 * 128 + ksl1)         = *(const bf16x8*)(ktb + (size_t)kr1 * 128 + kc * 8);
  *(bf16x8*)(lds + 16384 + vd0 * 64 + vsl0)  = *(const bf16x8*)(vtb + (size_t)vd0 * SMAX + vc * 8);
  *(bf16x8*)(lds + 16384 + vd1 * 64 + vsl1)  = *(const bf16x8*)(vtb + (size_t)vd1 * SMAX + vc * 8);
  __syncthreads();

  int off = 0;
  for (int st = 0; st < nt; ++st) {
    const int s0 = st * 64;
    bf16x8 nk0, nk1, nv0, nv1;
    const bool pre = (st + 1 < nt);
    if (pre) {
      const int s1 = s0 + 64;
      nk0 = *(const bf16x8*)(ktb + (size_t)(s1 + kr0) * 128 + kc * 8);
      nk1 = *(const bf16x8*)(ktb + (size_t)(s1 + kr1) * 128 + kc * 8);
      nv0 = *(const bf16x8*)(vtb + (size_t)vd0 * SMAX + s1 + vc * 8);
      nv1 = *(const bf16x8*)(vtb + (size_t)vd1 * SMAX + s1 + vc * 8);
      asm volatile("" ::: "memory");
    }
    const unsigned short* kl = lds + off;
    const unsigned short* vl = lds + 16384 + off;
    if (s0 <= wlim) {
#pragma unroll
      for (int sub = 0; sub < 2; ++sub) {
        const int ss = s0 + sub * 32;
        if (ss <= wlim) {
          floatx16 sa = {0,0,0,0,0,0,0,0,0,0,0,0,0,0,0,0};
          const unsigned short* kbase = kl + (sub * 32 + l31) * 128;
          const int kx = l31 & 15;
#pragma unroll
          for (int kg = 0; kg < 8; ++kg) {
            bf16x8 kf = *(const bf16x8*)(kbase + (((kg * 2 + hi) ^ kx) << 3));
            sa = __builtin_amdgcn_mfma_f32_32x32x16_bf16(kf, qf[kg], sa, 0, 0, 0);
          }
          if (ss + 31 > sp + wq0) {
#pragma unroll
            for (int r = 0; r < 16; ++r) {
              const int j = ss + (r & 3) + 8 * (r >> 2) + 4 * hi;
              if (j > lim) sa[r] = -1e30f;
            }
          }
          float mt = sa[0];
#pragma unroll
          for (int r = 1; r < 16; ++r) mt = fmaxf(mt, sa[r]);
          mt = fmaxf(mt, __shfl_xor(mt, 32, 64));
          if (!__all(mt <= mrun + 8.0f)) {
            const float mnew = fmaxf(mrun, mt);
            const float al = exp2f(mrun - mnew);
#pragma unroll
            for (int db = 0; db < 4; ++db)
#pragma unroll
              for (int r = 0; r < 16; ++r) oacc[db][r] *= al;
            lrun *= al;
            mrun = mnew;
          }
          float p[16]; float ls = 0.0f;
#pragma unroll
          for (int r = 0; r < 16; ++r) { p[r] = exp2f(sa[r] - mrun); ls += p[r]; }
          lrun += ls + __shfl_xor(ls, 32, 64);
#pragma unroll
          for (int ks = 0; ks < 2; ++ks) {
            const int rb = ks * 8;
            unsigned a0 = cvtpk_bf16(p[rb + 0], p[rb + 1]);
            unsigned a1 = cvtpk_bf16(p[rb + 2], p[rb + 3]);
            unsigned b0 = cvtpk_bf16(p[rb + 4], p[rb + 5]);
            unsigned b1 = cvtpk_bf16(p[rb + 6], p[rb + 7]);
            const unsigned t0 = __shfl_xor(a0, 32, 64);
            const unsigned t1 = __shfl_xor(b0, 32, 64);
            const unsigned t2 = __shfl_xor(a1, 32, 64);
            const unsigned t3 = __shfl_xor(b1, 32, 64);
            union { unsigned u[4]; bf16x8 v; } pf;
            pf.u[0] = hi ? t1 : a0;
            pf.u[1] = hi ? t3 : a1;
            pf.u[2] = hi ? b0 : t0;
            pf.u[3] = hi ? b1 : t2;
            const int sslot = sub * 4 + ks * 2 + hi;
#pragma unroll
            for (int db = 0; db < 4; ++db) {
              const int vrow = db * 32 + l31;
              bf16x8 vf = *(const bf16x8*)(vl + vrow * 64 + ((sslot ^ (l31 & 7)) << 3));
              oacc[db] = __builtin_amdgcn_mfma_f32_32x32x16_bf16(vf, pf.v, oacc[db], 0, 0, 0);
            }
          }
        }
      }
    }
    if (pre) {
      unsigned short* kn = lds + (off ^ 8192);
      unsigned short* vn = lds + 16384 + (off ^ 8192);
      *(bf16x8*)(kn + kr0 * 128 + ksl0) = nk0;
      *(bf16x8*)(kn + kr1 * 128 + ksl1) = nk1;
      *(bf16x8*)(vn + vd0 * 64 + vsl0) = nv0;
      *(bf16x8*)(vn + vd1 * 64 + vsl1) = nv1;
    }
    __syncthreads();
    off ^= 8192;
  }

  const float invl = 1.0f / lrun;
  unsigned short* myo = lds + w * 4096;
#pragma unroll
  for (int db = 0; db < 4; ++db)
#pragma unroll
    for (int i2 = 0; i2 < 8; ++i2) {
      const int r = i2 * 2;
      const int d = db * 32 + (r & 3) + 8 * (r >> 2) + 4 * hi;
      const unsigned wo = cvtpk_bf16(oacc[db][r] * invl, oacc[db][r + 1] * invl);
      *(unsigned*)(myo + l31 * 128 + (((2 * d) ^ ((l31 & 15) << 4)) >> 1)) = wo;
    }
  __syncthreads();
#pragma unroll
  for (int it = 0; it < 8; ++it) {
    const int c = tid + it * 512;
    const int wr = c >> 9, row = (c >> 4) & 31, c16 = c & 15;
    const int tq = (((wr < 4) ? x : (7 - x)) * 128) + (wr & 3) * 32 + row;
    bf16x8 vv = *(const bf16x8*)(lds + wr * 4096 + row * 128 + ((c16 ^ (row & 15)) << 3));
    *(bf16x8*)(ctx + ((size_t)(b * 1024 + tq)) * 4096 + h * 128 + c16 * 8) = vv;
  }
}

// ---------------------------------------------------------------------------
extern "C" void kernel_launch(void* const* d_in, const int* in_sizes, int n_in,
                              void* d_out, int out_size, void* d_ws, size_t ws_size,
                              hipStream_t stream) {
  const float* x  = (const float*)d_in[0];
  const int* sp   = (const int*)d_in[1];
  float* ck       = (float*)d_in[2];
  const float* cv = (const float*)d_in[3];
  const float* Wq = (const float*)d_in[4];
  const float* Wk = (const float*)d_in[5];
  const float* Wv = (const float*)d_in[6];
  const float* Wo = (const float*)d_in[7];
  float* out      = (float*)d_out;

  unsigned short* qb  = (unsigned short*)d_out;
  unsigned short* kt  = (unsigned short*)d_out + KT_OFF;
  unsigned short* vt  = (unsigned short*)d_out + VT_OFF;
  unsigned short* ws  = (unsigned short*)d_ws;
  unsigned short* xb  = ws + WS_XB;                 // shares [0,16.8MB) with ctx (disjoint lifetime)
  unsigned short* ctx = ws + WS_XB;
  float* tab          = ck + (size_t)2048 * 1024;   // unused cache_keys tail

  const bool full = ws_size >= WS_FULL_BYTES;

  rope_prep<<<256, 256, 0, stream>>>(sp, tab);
  convert_cache<<<dim3(16, 16), 256, 0, stream>>>(ck, cv, sp, kt, vt);

  if (full) {
    cvt_full<<<2048, 256, 0, stream>>>(x, Wq, Wk, Wv, Wo, ws);
    // QKV: BN=192 -> 32x16 = 512 blocks = exactly 2/CU (80KB LDS ring, 2x80=160KB)
    gemm_r2<1, 192><<<dim3(32, 16), 256, 0, stream>>>(xb, ws + WS_WQ, nullptr, qb, kt, vt, tab, sp);
    attn<<<dim3(4, 64), 512, 0, stream>>>(qb, kt, vt, sp, ctx);
    // Wo: BN=128 -> 32x16 = 512 blocks = exactly 2/CU (proven ~77us in round 3)
    gemm_r2<0, 128><<<dim3(32, 16), 256, 0, stream>>>(ctx, ws + WS_WO, out, nullptr, nullptr, nullptr,
                                                      nullptr, nullptr);
  } else {
    cvt_x<<<2048, 256, 0, stream>>>(x, xb);
    gemm_core<false, 1><<<dim3(48, 16), 256, 0, stream>>>(xb, nullptr, Wq, Wk, Wv,
                                                          nullptr, qb, kt, vt, tab, sp);
    attn<<<dim3(4, 64), 512, 0, stream>>>(qb, kt, vt, sp, ctx);
    gemm_core<false, 0><<<dim3(32, 16), 256, 0, stream>>>(ctx, nullptr, Wo, nullptr, nullptr,
                                                          out, nullptr, nullptr, nullptr, nullptr, nullptr);
  }
}